// Round 7
// baseline (363.714 us; speedup 1.0000x reference)
//
#include <hip/hip_runtime.h>

#define B_  2
#define C_  192
#define L_  4096
#define NH_ 8
#define HD_ 24
#define C3_ 576
#define KV_ 64
#define NSPL_ 4
#define LSPL_ (L_ / NSPL_)
#define NTS_ (LSPL_ / KV_)   // 16 tiles per block
#define HG_ 4                // heads per wave/block

typedef _Float16 f16;
typedef __attribute__((ext_vector_type(8))) f16 f16x8;
typedef __attribute__((ext_vector_type(16))) float f32x16;

#define L2E_ 1.4426950408889634f

__device__ __forceinline__ int pk2(float a, float b) {
    union { __fp16 h __attribute__((ext_vector_type(2))); int i; } u;
    u.h = __builtin_amdgcn_cvt_pkrtz(a, b);
    return u.i;
}
__device__ __forceinline__ int pk2_rte(float a, float b) {
    union { f16 h[2]; int i; } u;
    u.h[0] = (f16)a; u.h[1] = (f16)b;
    return u.i;
}
__device__ __forceinline__ float ex2(float x) {
    float r;
    asm("v_exp_f32 %0, %1" : "=v"(r) : "v"(x));
    return r;
}
__device__ __forceinline__ float lg2(float x) {
    float r;
    asm("v_log_f32 %0, %1" : "=v"(r) : "v"(x));
    return r;
}

union Frag { f16x8 v; int i[4]; };

#define MFMA32(A, Bx, Cc) __builtin_amdgcn_mfma_f32_32x32x16_f16((A), (Bx), (Cc), 0, 0, 0)

// async global -> LDS; LDS dest = wave-uniform base, HW adds lane*size
__device__ __forceinline__ void gload4(const void* g, void* lds) {
    typedef const unsigned int __attribute__((address_space(1))) as1u;
    typedef unsigned int __attribute__((address_space(3))) as3u;
    __builtin_amdgcn_global_load_lds((as1u*)g,
                                     (as3u*)(unsigned int)(unsigned long long)lds,
                                     4, 0, 0);
}
__device__ __forceinline__ void gload16(const void* g, void* lds) {
    typedef const unsigned int __attribute__((address_space(1))) as1u;
    typedef unsigned int __attribute__((address_space(3))) as3u;
    __builtin_amdgcn_global_load_lds((as1u*)g,
                                     (as3u*)(unsigned int)(unsigned long long)lds,
                                     16, 0, 0);
}

// ---------------------------------------------------------------------------
// QKV 1x1 conv -> packed f16 workspace.
// Q,K: half2 pair-words q2/k2[b][h][dp=0..11][L]  (Q pre-scaled by 8^-0.5*log2e)
// V:   plain f16        v16[b][h][d=0..23][L]
// ---------------------------------------------------------------------------
__global__ __launch_bounds__(256) void lin_qkv(const float* __restrict__ a,
                                               const float* __restrict__ w,
                                               const float* __restrict__ bias,
                                               unsigned int* __restrict__ q2,
                                               unsigned int* __restrict__ k2,
                                               unsigned short* __restrict__ v16) {
    __shared__ float wl[8][C_];
    const int og  = blockIdx.x;          // 0..71 (8 out-channels each)
    const int b   = blockIdx.y >> 4;
    const int lt  = blockIdx.y & 15;
    const int tid = threadIdx.x;

    for (int e = tid; e < 8 * C_; e += 256) wl[e / C_][e % C_] = w[og * 8 * C_ + e];
    __syncthreads();

    const int l = lt * 256 + tid;
    float acc[8];
#pragma unroll
    for (int j = 0; j < 8; ++j) acc[j] = bias[og * 8 + j];

    const float* ap = a + (size_t)b * C_ * L_ + l;
#pragma unroll 2
    for (int c = 0; c < C_; ++c) {
        const float xv = ap[(size_t)c * L_];
#pragma unroll
        for (int j = 0; j < 8; ++j) acc[j] = fmaf(wl[j][c], xv, acc[j]);
    }

    const float qscale = 0.35355339059327373f * L2E_;  // heads^-0.5 * log2e
    if (og < 48) {
        unsigned int* dst = (og < 24) ? q2 : k2;
        const int og_ = (og < 24) ? og : og - 24;
        const float sc = (og < 24) ? qscale : 1.f;
        const int h = og_ / 3, j0 = (og_ % 3) * 4;
        unsigned int* p = dst + ((size_t)(b * NH_ + h) * 12 + j0) * L_ + l;
#pragma unroll
        for (int j = 0; j < 4; ++j)
            p[(size_t)j * L_] = pk2_rte(acc[2 * j] * sc, acc[2 * j + 1] * sc);
    } else {
        const int og_ = og - 48;
        const int h = og_ / 3, d0 = (og_ % 3) * 8;
        unsigned short* p = v16 + ((size_t)(b * NH_ + h) * 24 + d0) * L_ + l;
#pragma unroll
        for (int j = 0; j < 8; ++j) {
            union { f16 hf; unsigned short us; } cv;
            cv.hf = (f16)acc[j];
            p[(size_t)j * L_] = cv.us;
        }
    }
}

// ---------------------------------------------------------------------------
// f32 per-pixel linear (output projection)
// ---------------------------------------------------------------------------
__global__ __launch_bounds__(256) void lin_kernel(const float* __restrict__ a,
                                                  const float* __restrict__ w,
                                                  const float* __restrict__ bias,
                                                  float* __restrict__ out, int OC) {
    __shared__ float wl[8][C_];
    const int og  = blockIdx.x;
    const int b   = blockIdx.y >> 4;
    const int lt  = blockIdx.y & 15;
    const int tid = threadIdx.x;

    for (int e = tid; e < 8 * C_; e += 256) wl[e / C_][e % C_] = w[og * 8 * C_ + e];
    __syncthreads();

    const int l = lt * 256 + tid;
    float acc[8];
#pragma unroll
    for (int j = 0; j < 8; ++j) acc[j] = bias[og * 8 + j];

    const float* ap = a + (size_t)b * C_ * L_ + l;
#pragma unroll 2
    for (int c = 0; c < C_; ++c) {
        const float xv = ap[(size_t)c * L_];
#pragma unroll
        for (int j = 0; j < 8; ++j) acc[j] = fmaf(wl[j][c], xv, acc[j]);
    }

    float* op = out + ((size_t)b * OC + og * 8) * L_ + l;
#pragma unroll
    for (int j = 0; j < 8; ++j) op[(size_t)j * L_] = acc[j];
}

// ---------------------------------------------------------------------------
// MFMA f16 flash attention — HEAD-SHARED MASK version.
// Wave = 32 q-rows x 4 heads. Mask tile loaded to regs ONCE per tile, used as
// the MFMA C-initializer for all 4 heads (zero-copy). K/V for the 4 heads
// staged cooperatively (wave w stages head w) via global_load_lds, double-
// buffered, one drain barrier per 64-key tile. Softmax in log2 domain.
// Grid 512: bid = ((sp*2+hg)*2+b)*32 + qt.  KV-split x4, combine kernel merges.
// ---------------------------------------------------------------------------
__global__ __launch_bounds__(256) void attn_mfma(const unsigned int* __restrict__ q2,
                                                 const unsigned int* __restrict__ k2,
                                                 const unsigned short* __restrict__ v16,
                                                 const float* __restrict__ mask,
                                                 unsigned short* __restrict__ po,
                                                 float* __restrict__ pms) {
    const int tid  = threadIdx.x;
    const int lane = tid & 63;
    const int wid  = tid >> 6;
    const int hi   = lane >> 5;
    const int lq   = lane & 31;
    const int bid  = blockIdx.x;
    const int qt   = bid & 31;
    const int r    = bid >> 5;
    const int b    = r & 1;
    const int hg   = (r >> 1) & 1;
    const int sp   = r >> 2;
    const int qrow = qt * 128 + wid * 32 + lq;
    const int kv0  = sp * LSPL_;
    const int hbase = hg * HG_;

    __shared__ int k_lds[2][HG_][16][64];  // rows 12..15 zeroed (contraction pad)
    __shared__ int v_lds[2][HG_][32][32];  // rows 24..31 garbage -> dropped O rows

    // zero K pad rows (8 head-bufs x 256 words), before first barrier
#pragma unroll
    for (int z = 0; z < 8; ++z) {
        const int wd = z * 256 + tid;
        k_lds[wd >> 10][(wd >> 8) & 3][12 + ((wd >> 6) & 3)][wd & 63] = 0;
    }

    const unsigned int*   qb   = q2  + (size_t)(b * NH_ + hbase) * 12 * L_;
    const unsigned int*   kb_w = k2  + (size_t)(b * NH_ + hbase + wid) * 12 * L_;
    const unsigned short* vb_w = v16 + (size_t)(b * NH_ + hbase + wid) * 24 * L_;
    const float* mrow = mask + ((size_t)b * L_ + qrow) * L_;

    // Q fragments for 4 heads (zero where dpq >= 12)
    int bq[HG_][8];
#pragma unroll
    for (int H = 0; H < HG_; ++H)
#pragma unroll
        for (int s = 0; s < 2; ++s)
#pragma unroll
            for (int t = 0; t < 4; ++t) {
                const int dpq = 8 * s + 4 * hi + t;
                bq[H][s * 4 + t] = (dpq < 12) ? qb[(size_t)(H * 12 + dpq) * L_ + qrow] : 0;
            }

#define STAGE(BF, KK) do {                                                    \
    _Pragma("unroll")                                                         \
    for (int j_ = 0; j_ < 3; ++j_) {                                          \
        const int dp_ = j_ * 4 + (lane >> 4);                                 \
        gload16(kb_w + (size_t)dp_ * L_ + (KK) + 4 * (lane & 15),             \
                &k_lds[BF][wid][0][0] + j_ * 256);                            \
    }                                                                         \
    _Pragma("unroll")                                                         \
    for (int j_ = 0; j_ < 12; ++j_) {                                         \
        const int e_ = j_ * 64 + lane;                                        \
        const int d_ = e_ >> 5, sl_ = e_ & 31;                                \
        gload4(vb_w + (size_t)d_ * L_ + (KK) + 2 * (sl_ ^ d_),                \
               &v_lds[BF][wid][0][0] + j_ * 64);                              \
    } } while (0)

#define MLOADX(KK) do {                                                       \
    const float4* mb_ = (const float4*)(mrow + (KK));                         \
    _Pragma("unroll")                                                         \
    for (int q_ = 0; q_ < 4; ++q_) {                                          \
        const float4 t0_ = mb_[2 * q_ + hi];                                  \
        mr0[4 * q_ + 0] = t0_.x; mr0[4 * q_ + 1] = t0_.y;                     \
        mr0[4 * q_ + 2] = t0_.z; mr0[4 * q_ + 3] = t0_.w;                     \
        const float4 t1_ = mb_[8 + 2 * q_ + hi];                              \
        mr1[4 * q_ + 0] = t1_.x; mr1[4 * q_ + 1] = t1_.y;                     \
        mr1[4 * q_ + 2] = t1_.z; mr1[4 * q_ + 3] = t1_.w;                     \
    } } while (0)

#define MSCALE do {                                                           \
    _Pragma("unroll")                                                         \
    for (int i_ = 0; i_ < 16; ++i_) { mr0[i_] *= L2E_; mr1[i_] *= L2E_; }     \
    } while (0)

#define QKH(H, BF) do {                                                       \
    Frag qf0, qf1, ka0, ka1;                                                  \
    _Pragma("unroll")                                                         \
    for (int t_ = 0; t_ < 4; ++t_) { qf0.i[t_] = bq[H][t_]; qf1.i[t_] = bq[H][4 + t_]; } \
    _Pragma("unroll")                                                         \
    for (int t_ = 0; t_ < 4; ++t_) {                                          \
        ka0.i[t_] = k_lds[BF][H][4 * hi + t_][lq];                            \
        ka1.i[t_] = k_lds[BF][H][8 + 4 * hi + t_][lq];                        \
    }                                                                         \
    __builtin_amdgcn_s_setprio(1);                                            \
    c0 = MFMA32(ka0.v, qf0.v, mr0);                                           \
    c0 = MFMA32(ka1.v, qf1.v, c0);                                            \
    __builtin_amdgcn_s_setprio(0);                                            \
    _Pragma("unroll")                                                         \
    for (int t_ = 0; t_ < 4; ++t_) {                                          \
        ka0.i[t_] = k_lds[BF][H][4 * hi + t_][32 + lq];                       \
        ka1.i[t_] = k_lds[BF][H][8 + 4 * hi + t_][32 + lq];                   \
    }                                                                         \
    __builtin_amdgcn_s_setprio(1);                                            \
    c1 = MFMA32(ka0.v, qf0.v, mr1);                                           \
    c1 = MFMA32(ka1.v, qf1.v, c1);                                            \
    __builtin_amdgcn_s_setprio(0);                                            \
    } while (0)

#define PVSTEP(BF, H, CU, U) do {                                             \
    int w1[4], w2[4], s1[4], s2[4];                                           \
    _Pragma("unroll")                                                         \
    for (int q_ = 0; q_ < 4; ++q_) {                                          \
        w1[q_] = pk2(CU[4 * q_], CU[4 * q_ + 1]);                             \
        w2[q_] = pk2(CU[4 * q_ + 2], CU[4 * q_ + 3]);                         \
    }                                                                         \
    _Pragma("unroll")                                                         \
    for (int q_ = 0; q_ < 4; ++q_) {                                          \
        s1[q_] = __shfl_xor(w1[q_], 32);                                      \
        s2[q_] = __shfl_xor(w2[q_], 32);                                      \
    }                                                                         \
    _Pragma("unroll")                                                         \
    for (int s_ = 0; s_ < 2; ++s_) {                                          \
        const int qq_ = 2 * s_ + hi;                                          \
        Frag pb, va;                                                          \
        pb.i[0] = hi ? s1[qq_] : w1[qq_];                                     \
        pb.i[1] = hi ? s2[qq_] : w2[qq_];                                     \
        pb.i[2] = hi ? w1[qq_] : s1[qq_];                                     \
        pb.i[3] = hi ? w2[qq_] : s2[qq_];                                     \
        _Pragma("unroll")                                                     \
        for (int t_ = 0; t_ < 4; ++t_)                                        \
            va.i[t_] = v_lds[BF][H][lq][(16 * U + 8 * s_ + 4 * hi + t_) ^ lq]; \
        __builtin_amdgcn_s_setprio(1);                                        \
        o[H] = MFMA32(va.v, pb.v, o[H]);                                      \
        __builtin_amdgcn_s_setprio(0);                                        \
    } } while (0)

#define SMPV(H, BF) do {                                                      \
    float pmax = c0[0];                                                       \
    _Pragma("unroll")                                                         \
    for (int i_ = 1; i_ < 16; ++i_) pmax = fmaxf(pmax, c0[i_]);               \
    _Pragma("unroll")                                                         \
    for (int i_ = 0; i_ < 16; ++i_) pmax = fmaxf(pmax, c1[i_]);               \
    pmax = fmaxf(pmax, __shfl_xor(pmax, 32));                                 \
    if (!__all((int)(pmax <= mrun[H] + 11.5415603f))) {                       \
        const float newm_ = fmaxf(mrun[H], pmax);                             \
        const float r_ = ex2(mrun[H] - newm_);                                \
        srun[H] *= r_;                                                        \
        _Pragma("unroll")                                                     \
        for (int i_ = 0; i_ < 16; ++i_) o[H][i_] *= r_;                       \
        mrun[H] = newm_;                                                      \
    }                                                                         \
    float ls = 0.f;                                                           \
    _Pragma("unroll")                                                         \
    for (int i_ = 0; i_ < 16; ++i_) { c0[i_] = ex2(c0[i_] - mrun[H]); ls += c0[i_]; } \
    _Pragma("unroll")                                                         \
    for (int i_ = 0; i_ < 16; ++i_) { c1[i_] = ex2(c1[i_] - mrun[H]); ls += c1[i_]; } \
    ls += __shfl_xor(ls, 32);                                                 \
    srun[H] += ls;                                                            \
    PVSTEP(BF, H, c0, 0);                                                     \
    PVSTEP(BF, H, c1, 1);                                                     \
    } while (0)

    f32x16 o[HG_];
    float mrun[HG_], srun[HG_];
#pragma unroll
    for (int H = 0; H < HG_; ++H) {
#pragma unroll
        for (int i = 0; i < 16; ++i) o[H][i] = 0.f;
        mrun[H] = -1e30f;
        srun[H] = 0.f;
    }
    f32x16 mr0, mr1, c0, c1;

    STAGE(0, kv0);
    MLOADX(kv0);
    __syncthreads();   // drain: tile 0 K/V + mask landed

#pragma clang loop unroll(disable)
    for (int t = 0; t < NTS_; ++t) {
        const int kk = kv0 + t * KV_;
        const int cur = t & 1;
        if (t + 1 < NTS_) STAGE(cur ^ 1, kk + KV_);
        MSCALE;
        QKH(0, cur); SMPV(0, cur);
        QKH(1, cur); SMPV(1, cur);
        QKH(2, cur); SMPV(2, cur);
        QKH(3, cur);
        if (t + 1 < NTS_) MLOADX(kk + KV_);   // WAR on mr: issues after QKH(3) C-in
        SMPV(3, cur);
        __syncthreads();                      // drain: next tile K/V + mask landed
    }

    // ---- partial epilogue per head: normalized O (f16) + lse (f32, log2) ----
#pragma unroll
    for (int H = 0; H < HG_; ++H) {
        const float inv = 1.f / srun[H];
        const float lse = mrun[H] + lg2(srun[H]);
        unsigned short* pob = po + ((size_t)((sp * B_ + b) * NH_ + hbase + H) * HD_) * L_ + qrow;
#pragma unroll
        for (int i = 0; i < 16; ++i) {
            const int d = (i & 3) + 8 * (i >> 2) + 4 * hi;
            if (d < HD_) {
                union { __fp16 hf; unsigned short us; } cv;
                cv.hf = (__fp16)(o[H][i] * inv);
                pob[(size_t)d * L_] = cv.us;
            }
        }
        if (hi == 0)
            pms[((size_t)(sp * B_ + b) * NH_ + hbase + H) * L_ + qrow] = lse;
    }
#undef STAGE
#undef MLOADX
#undef MSCALE
#undef QKH
#undef PVSTEP
#undef SMPV
}

// ---------------------------------------------------------------------------
// Combine the 4 KV-split partials.
// ---------------------------------------------------------------------------
__global__ __launch_bounds__(256) void combine_kernel(const unsigned short* __restrict__ po,
                                                      const float* __restrict__ pms,
                                                      float* __restrict__ att) {
    const int qrow = blockIdx.x * 256 + threadIdx.x;
    const int h    = blockIdx.y;
    const int b    = blockIdx.z;

    float l[NSPL_];
#pragma unroll
    for (int s = 0; s < NSPL_; ++s)
        l[s] = pms[((size_t)(s * B_ + b) * NH_ + h) * L_ + qrow];
    float lm = l[0];
#pragma unroll
    for (int s = 1; s < NSPL_; ++s) lm = fmaxf(lm, l[s]);
    float wv[NSPL_], wsum = 0.f;
#pragma unroll
    for (int s = 0; s < NSPL_; ++s) { wv[s] = ex2(l[s] - lm); wsum += wv[s]; }
    const float inv = 1.f / wsum;

    float* op = att + ((size_t)b * C_ + h * HD_) * L_ + qrow;
#pragma unroll
    for (int d = 0; d < HD_; ++d) {
        float acc = 0.f;
#pragma unroll
        for (int s = 0; s < NSPL_; ++s) {
            union { unsigned short us; __fp16 hf; } cv;
            cv.us = po[(((size_t)(s * B_ + b) * NH_ + h) * HD_ + d) * L_ + qrow];
            acc += (float)cv.hf * wv[s];
        }
        op[(size_t)d * L_] = acc * inv;
    }
}

// ---------------------------------------------------------------------------
extern "C" void kernel_launch(void* const* d_in, const int* in_sizes, int n_in,
                              void* d_out, int out_size, void* d_ws, size_t ws_size,
                              hipStream_t stream) {
    const float* x      = (const float*)d_in[0];
    const float* mask   = (const float*)d_in[1];
    const float* w_qkv  = (const float*)d_in[2];
    const float* b_qkv  = (const float*)d_in[3];
    const float* w_proj = (const float*)d_in[4];
    const float* b_proj = (const float*)d_in[5];
    float* out = (float*)d_out;

    unsigned int*   q2  = (unsigned int*)d_ws;                                // B*8*12*L u32
    unsigned int*   k2  = q2 + (size_t)B_ * NH_ * 12 * L_;                    // B*8*12*L u32
    unsigned short* v16 = (unsigned short*)(k2 + (size_t)B_ * NH_ * 12 * L_); // B*8*24*L u16
    unsigned short* po  = v16 + (size_t)B_ * NH_ * HD_ * L_;                  // 4*B*8*24*L u16
    float* pms    = (float*)(po + (size_t)NSPL_ * B_ * NH_ * HD_ * L_);       // 4*B*8*L f32
    float* ws_att = pms + (size_t)NSPL_ * B_ * NH_ * L_;                      // B*192*L f32

    lin_qkv<<<dim3(72, 32), 256, 0, stream>>>(x, w_qkv, b_qkv, q2, k2, v16);
    attn_mfma<<<dim3(512), 256, 0, stream>>>(q2, k2, v16, mask, po, pms);
    combine_kernel<<<dim3(16, NH_, B_), 256, 0, stream>>>(po, pms, ws_att);
    lin_kernel<<<dim3(24, 32), 256, 0, stream>>>(ws_att, w_proj, b_proj, out, C_);
}

// Round 8
// 354.022 us; speedup vs baseline: 1.0274x; 1.0274x over previous
//
#include <hip/hip_runtime.h>

#define B_  2
#define C_  192
#define L_  4096
#define NH_ 8
#define HD_ 24
#define C3_ 576
#define KV_ 64
#define NSPL_ 4
#define LSPL_ (L_ / NSPL_)
#define NTS_ (LSPL_ / KV_)   // 16 tiles per block
#define HG_ 4                // heads per wave/block
#define KSTR_ 20             // K row stride in words (64B data + 16B pad)

typedef _Float16 f16;
typedef __attribute__((ext_vector_type(8))) f16 f16x8;
typedef __attribute__((ext_vector_type(16))) float f32x16;

#define L2E_ 1.4426950408889634f

__device__ __forceinline__ int pk2(float a, float b) {
    union { __fp16 h __attribute__((ext_vector_type(2))); int i; } u;
    u.h = __builtin_amdgcn_cvt_pkrtz(a, b);
    return u.i;
}
__device__ __forceinline__ int pk2_rte(float a, float b) {
    union { f16 h[2]; int i; } u;
    u.h[0] = (f16)a; u.h[1] = (f16)b;
    return u.i;
}
__device__ __forceinline__ float ex2(float x) {
    float r;
    asm("v_exp_f32 %0, %1" : "=v"(r) : "v"(x));
    return r;
}
__device__ __forceinline__ float lg2(float x) {
    float r;
    asm("v_log_f32 %0, %1" : "=v"(r) : "v"(x));
    return r;
}

union Frag { f16x8 v; int i[4]; };

#define MFMA32(A, Bx, Cc) __builtin_amdgcn_mfma_f32_32x32x16_f16((A), (Bx), (Cc), 0, 0, 0)

// async global -> LDS; LDS dest = wave-uniform base, HW adds lane*size
__device__ __forceinline__ void gload4(const void* g, void* lds) {
    typedef const unsigned int __attribute__((address_space(1))) as1u;
    typedef unsigned int __attribute__((address_space(3))) as3u;
    __builtin_amdgcn_global_load_lds((as1u*)g,
                                     (as3u*)(unsigned int)(unsigned long long)lds,
                                     4, 0, 0);
}
__device__ __forceinline__ void gload16(const void* g, void* lds) {
    typedef const unsigned int __attribute__((address_space(1))) as1u;
    typedef unsigned int __attribute__((address_space(3))) as3u;
    __builtin_amdgcn_global_load_lds((as1u*)g,
                                     (as3u*)(unsigned int)(unsigned long long)lds,
                                     16, 0, 0);
}

// ---------------------------------------------------------------------------
// QKV 1x1 conv -> packed f16 workspace.
// Q:   half2 pair-words q2[b][h][dp=0..11][L]   (pre-scaled by 8^-0.5*log2e)
// K:   key-major padded k2t[b][h][key][KSTR_=20 words]: words 0..11 = dp pairs,
//      words 12..19 = ZERO (so gload16 staging is linear and pads are safe)
// V:   plain f16 v16[b][h][d=0..23][L]
// ---------------------------------------------------------------------------
__global__ __launch_bounds__(256) void lin_qkv(const float* __restrict__ a,
                                               const float* __restrict__ w,
                                               const float* __restrict__ bias,
                                               unsigned int* __restrict__ q2,
                                               unsigned int* __restrict__ k2t,
                                               unsigned short* __restrict__ v16) {
    __shared__ float wl[8][C_];
    const int og  = blockIdx.x;          // 0..71 (8 out-channels each)
    const int b   = blockIdx.y >> 4;
    const int lt  = blockIdx.y & 15;
    const int tid = threadIdx.x;

    for (int e = tid; e < 8 * C_; e += 256) wl[e / C_][e % C_] = w[og * 8 * C_ + e];
    __syncthreads();

    const int l = lt * 256 + tid;
    float acc[8];
#pragma unroll
    for (int j = 0; j < 8; ++j) acc[j] = bias[og * 8 + j];

    const float* ap = a + (size_t)b * C_ * L_ + l;
#pragma unroll 2
    for (int c = 0; c < C_; ++c) {
        const float xv = ap[(size_t)c * L_];
#pragma unroll
        for (int j = 0; j < 8; ++j) acc[j] = fmaf(wl[j][c], xv, acc[j]);
    }

    const float qscale = 0.35355339059327373f * L2E_;  // heads^-0.5 * log2e
    if (og < 24) {               // Q
        const int h = og / 3, j0 = (og % 3) * 4;
        unsigned int* p = q2 + ((size_t)(b * NH_ + h) * 12 + j0) * L_ + l;
#pragma unroll
        for (int j = 0; j < 4; ++j)
            p[(size_t)j * L_] = pk2_rte(acc[2 * j] * qscale, acc[2 * j + 1] * qscale);
    } else if (og < 48) {        // K -> key-major padded
        const int og_ = og - 24;
        const int h = og_ / 3, j0 = (og_ % 3) * 4;
        unsigned int* p = k2t + ((size_t)(b * NH_ + h) * L_ + l) * KSTR_ + j0;
        int4 v;
        v.x = pk2_rte(acc[0], acc[1]); v.y = pk2_rte(acc[2], acc[3]);
        v.z = pk2_rte(acc[4], acc[5]); v.w = pk2_rte(acc[6], acc[7]);
        *(int4*)p = v;
        if (j0 == 8) {           // zero pad words 12..19 exactly once per key
            int4 z; z.x = z.y = z.z = z.w = 0;
            *(int4*)(p + 4) = z;
            *(int4*)(p + 8) = z;
        }
    } else {                     // V
        const int og_ = og - 48;
        const int h = og_ / 3, d0 = (og_ % 3) * 8;
        unsigned short* p = v16 + ((size_t)(b * NH_ + h) * 24 + d0) * L_ + l;
#pragma unroll
        for (int j = 0; j < 8; ++j) {
            union { f16 hf; unsigned short us; } cv;
            cv.hf = (f16)acc[j];
            p[(size_t)j * L_] = cv.us;
        }
    }
}

// ---------------------------------------------------------------------------
// f32 per-pixel linear (output projection)
// ---------------------------------------------------------------------------
__global__ __launch_bounds__(256) void lin_kernel(const float* __restrict__ a,
                                                  const float* __restrict__ w,
                                                  const float* __restrict__ bias,
                                                  float* __restrict__ out, int OC) {
    __shared__ float wl[8][C_];
    const int og  = blockIdx.x;
    const int b   = blockIdx.y >> 4;
    const int lt  = blockIdx.y & 15;
    const int tid = threadIdx.x;

    for (int e = tid; e < 8 * C_; e += 256) wl[e / C_][e % C_] = w[og * 8 * C_ + e];
    __syncthreads();

    const int l = lt * 256 + tid;
    float acc[8];
#pragma unroll
    for (int j = 0; j < 8; ++j) acc[j] = bias[og * 8 + j];

    const float* ap = a + (size_t)b * C_ * L_ + l;
#pragma unroll 2
    for (int c = 0; c < C_; ++c) {
        const float xv = ap[(size_t)c * L_];
#pragma unroll
        for (int j = 0; j < 8; ++j) acc[j] = fmaf(wl[j][c], xv, acc[j]);
    }

    float* op = out + ((size_t)b * OC + og * 8) * L_ + l;
#pragma unroll
    for (int j = 0; j < 8; ++j) op[(size_t)j * L_] = acc[j];
}

// ---------------------------------------------------------------------------
// MFMA f16 flash attention — head-shared mask + short-chain ILP version.
// Wave = 32 q-rows x 4 heads. Per tile: heads processed in 2 independent
// pairs (one basic block each) so the compiler interleaves their chains.
// K in LDS key-major [64][20w] (b128 frags, bank-spread by 80B stride).
// V in LDS [d][kp] with group-XOR swizzle (b128 frags).
// Branchless online softmax (log2 domain), tree reductions.
// Grid 512: bid = ((sp*2+hg)*2+b)*32 + qt.  KV-split x4, combine merges.
// ---------------------------------------------------------------------------
__global__ __launch_bounds__(256) void attn_mfma(const unsigned int* __restrict__ q2,
                                                 const unsigned int* __restrict__ k2t,
                                                 const unsigned short* __restrict__ v16,
                                                 const float* __restrict__ mask,
                                                 unsigned short* __restrict__ po,
                                                 float* __restrict__ pms) {
    const int tid  = threadIdx.x;
    const int lane = tid & 63;
    const int wid  = tid >> 6;
    const int hi   = lane >> 5;
    const int lq   = lane & 31;
    const int bid  = blockIdx.x;
    const int qt   = bid & 31;
    const int r    = bid >> 5;
    const int b    = r & 1;
    const int hg   = (r >> 1) & 1;
    const int sp   = r >> 2;
    const int qrow = qt * 128 + wid * 32 + lq;
    const int kv0  = sp * LSPL_;
    const int hbase = hg * HG_;

    __shared__ __attribute__((aligned(16))) int k_lds[2][HG_][64 * KSTR_];
    __shared__ __attribute__((aligned(16))) int v_lds[2][HG_][32 * 32];

    const unsigned int*   qb   = q2  + (size_t)(b * NH_ + hbase) * 12 * L_;
    const unsigned int*   kb_w = k2t + (size_t)(b * NH_ + hbase + wid) * L_ * KSTR_;
    const unsigned short* vb_w = v16 + (size_t)(b * NH_ + hbase + wid) * 24 * L_;
    const float* mrow = mask + ((size_t)b * L_ + qrow) * L_;

    // Q fragments for 4 heads (zero where dpq >= 12 -> K pad contributes 0)
    int bq[HG_][8];
#pragma unroll
    for (int H = 0; H < HG_; ++H)
#pragma unroll
        for (int s = 0; s < 2; ++s)
#pragma unroll
            for (int t = 0; t < 4; ++t) {
                const int dpq = 8 * s + 4 * hi + t;
                bq[H][s * 4 + t] = (dpq < 12) ? qb[(size_t)(H * 12 + dpq) * L_ + qrow] : 0;
            }

#define STAGE(BF, KK) do {                                                    \
    const char* ksrc_ = (const char*)kb_w + (size_t)(KK) * 80 + (size_t)lane * 16; \
    char* kdst_ = (char*)&k_lds[BF][wid][0];                                  \
    _Pragma("unroll")                                                         \
    for (int j_ = 0; j_ < 5; ++j_)                                            \
        gload16(ksrc_ + j_ * 1024, kdst_ + j_ * 1024);                        \
    _Pragma("unroll")                                                         \
    for (int j_ = 0; j_ < 12; ++j_) {                                         \
        const int d_ = j_ * 2 + (lane >> 5);                                  \
        const int c_ = lane & 31;                                             \
        const int kp_ = ((((c_ >> 2) ^ (d_ & 7)) << 2) | (c_ & 3));           \
        gload4(vb_w + (size_t)d_ * L_ + (KK) + 2 * kp_,                       \
               (char*)&v_lds[BF][wid][0] + j_ * 256);                         \
    } } while (0)

#define MLOADX(KK) do {                                                       \
    const float4* mb_ = (const float4*)(mrow + (KK));                         \
    _Pragma("unroll")                                                         \
    for (int q_ = 0; q_ < 4; ++q_) {                                          \
        const float4 t0_ = mb_[2 * q_ + hi];                                  \
        mr0[4 * q_ + 0] = t0_.x; mr0[4 * q_ + 1] = t0_.y;                     \
        mr0[4 * q_ + 2] = t0_.z; mr0[4 * q_ + 3] = t0_.w;                     \
        const float4 t1_ = mb_[8 + 2 * q_ + hi];                              \
        mr1[4 * q_ + 0] = t1_.x; mr1[4 * q_ + 1] = t1_.y;                     \
        mr1[4 * q_ + 2] = t1_.z; mr1[4 * q_ + 3] = t1_.w;                     \
    } } while (0)

#define MSCALE do {                                                           \
    _Pragma("unroll")                                                         \
    for (int i_ = 0; i_ < 16; ++i_) { mr0[i_] *= L2E_; mr1[i_] *= L2E_; }     \
    } while (0)

// QK^T for one head: 4 ds_read_b128 + 4 MFMA. C0 keys 0..31, C1 keys 32..63.
#define QKH(BF, H, C0, C1) do {                                               \
    Frag qf0, qf1, ka;                                                        \
    _Pragma("unroll")                                                         \
    for (int t_ = 0; t_ < 4; ++t_) { qf0.i[t_] = bq[H][t_]; qf1.i[t_] = bq[H][4 + t_]; } \
    const int* kb_ = &k_lds[BF][H][0];                                        \
    ka.v = *(const f16x8*)(kb_ + lq * KSTR_ + 4 * hi);                        \
    C0 = MFMA32(ka.v, qf0.v, mr0);                                            \
    ka.v = *(const f16x8*)(kb_ + lq * KSTR_ + 8 + 4 * hi);                    \
    C0 = MFMA32(ka.v, qf1.v, C0);                                             \
    ka.v = *(const f16x8*)(kb_ + (32 + lq) * KSTR_ + 4 * hi);                 \
    C1 = MFMA32(ka.v, qf0.v, mr1);                                            \
    ka.v = *(const f16x8*)(kb_ + (32 + lq) * KSTR_ + 8 + 4 * hi);             \
    C1 = MFMA32(ka.v, qf1.v, C1);                                             \
    } while (0)

// Branchless online softmax (log2 domain), tree reductions.
#define SMH(H, C0, C1) do {                                                   \
    float m8[8], m4[4], m2[2];                                                \
    _Pragma("unroll")                                                         \
    for (int i_ = 0; i_ < 8; ++i_)                                            \
        m8[i_] = fmaxf(fmaxf(C0[i_], C0[i_ + 8]), fmaxf(C1[i_], C1[i_ + 8])); \
    _Pragma("unroll")                                                         \
    for (int i_ = 0; i_ < 4; ++i_) m4[i_] = fmaxf(m8[i_], m8[i_ + 4]);        \
    m2[0] = fmaxf(m4[0], m4[2]); m2[1] = fmaxf(m4[1], m4[3]);                 \
    float pmax = fmaxf(m2[0], m2[1]);                                         \
    pmax = fmaxf(pmax, __shfl_xor(pmax, 32));                                 \
    const float newm_ = fmaxf(mrun[H], pmax);                                 \
    const float r_ = ex2(mrun[H] - newm_);                                    \
    mrun[H] = newm_;                                                          \
    srun[H] *= r_;                                                            \
    _Pragma("unroll")                                                         \
    for (int i_ = 0; i_ < 16; ++i_) o[H][i_] *= r_;                           \
    _Pragma("unroll")                                                         \
    for (int i_ = 0; i_ < 16; ++i_) C0[i_] = ex2(C0[i_] - newm_);             \
    _Pragma("unroll")                                                         \
    for (int i_ = 0; i_ < 16; ++i_) C1[i_] = ex2(C1[i_] - newm_);             \
    float s8[8], s4[4];                                                       \
    _Pragma("unroll")                                                         \
    for (int i_ = 0; i_ < 8; ++i_)                                            \
        s8[i_] = (C0[i_] + C0[i_ + 8]) + (C1[i_] + C1[i_ + 8]);               \
    _Pragma("unroll")                                                         \
    for (int i_ = 0; i_ < 4; ++i_) s4[i_] = s8[i_] + s8[i_ + 4];              \
    float ls = (s4[0] + s4[2]) + (s4[1] + s4[3]);                             \
    ls += __shfl_xor(ls, 32);                                                 \
    srun[H] += ls;                                                            \
    } while (0)

// PV for one head: pack P->f16, half-exchange, 4 ds_read_b128 + 4 MFMA.
#define PVH(BF, H, C0, C1) do {                                               \
    int wa1[4], wa2[4], sa1[4], sa2[4];                                       \
    int wb1[4], wb2[4], sb1[4], sb2[4];                                       \
    _Pragma("unroll")                                                         \
    for (int q_ = 0; q_ < 4; ++q_) {                                          \
        wa1[q_] = pk2(C0[4 * q_], C0[4 * q_ + 1]);                            \
        wa2[q_] = pk2(C0[4 * q_ + 2], C0[4 * q_ + 3]);                        \
        wb1[q_] = pk2(C1[4 * q_], C1[4 * q_ + 1]);                            \
        wb2[q_] = pk2(C1[4 * q_ + 2], C1[4 * q_ + 3]);                        \
    }                                                                         \
    _Pragma("unroll")                                                         \
    for (int q_ = 0; q_ < 4; ++q_) {                                          \
        sa1[q_] = __shfl_xor(wa1[q_], 32); sa2[q_] = __shfl_xor(wa2[q_], 32); \
        sb1[q_] = __shfl_xor(wb1[q_], 32); sb2[q_] = __shfl_xor(wb2[q_], 32); \
    }                                                                         \
    const int* vb_ = &v_lds[BF][H][0];                                        \
    _Pragma("unroll")                                                         \
    for (int s_ = 0; s_ < 2; ++s_) {                                          \
        const int qq_ = 2 * s_ + hi;                                          \
        Frag pb, va;                                                          \
        pb.i[0] = hi ? sa1[qq_] : wa1[qq_];                                   \
        pb.i[1] = hi ? sa2[qq_] : wa2[qq_];                                   \
        pb.i[2] = hi ? wa1[qq_] : sa1[qq_];                                   \
        pb.i[3] = hi ? wa2[qq_] : sa2[qq_];                                   \
        va.v = *(const f16x8*)(vb_ + lq * 32 + (((2 * s_ + hi) ^ (lq & 7)) << 2)); \
        o[H] = MFMA32(va.v, pb.v, o[H]);                                      \
        pb.i[0] = hi ? sb1[qq_] : wb1[qq_];                                   \
        pb.i[1] = hi ? sb2[qq_] : wb2[qq_];                                   \
        pb.i[2] = hi ? wb1[qq_] : sb1[qq_];                                   \
        pb.i[3] = hi ? wb2[qq_] : sb2[qq_];                                   \
        va.v = *(const f16x8*)(vb_ + lq * 32 + (((4 + 2 * s_ + hi) ^ (lq & 7)) << 2)); \
        o[H] = MFMA32(va.v, pb.v, o[H]);                                      \
    } } while (0)

    f32x16 o[HG_];
    float mrun[HG_], srun[HG_];
#pragma unroll
    for (int H = 0; H < HG_; ++H) {
#pragma unroll
        for (int i = 0; i < 16; ++i) o[H][i] = 0.f;
        mrun[H] = -1e30f;
        srun[H] = 0.f;
    }
    f32x16 mr0, mr1, cA0, cA1, cB0, cB1;

    STAGE(0, kv0);
    MLOADX(kv0);
    __syncthreads();   // drain: tile 0 K/V + mask landed

#pragma clang loop unroll(disable)
    for (int t = 0; t < NTS_; ++t) {
        const int kk = kv0 + t * KV_;
        const int cur = t & 1;
        if (t + 1 < NTS_) STAGE(cur ^ 1, kk + KV_);
        MSCALE;
        // head pair {0,1}: two independent chains in one basic block
        QKH(cur, 0, cA0, cA1);
        QKH(cur, 1, cB0, cB1);
        SMH(0, cA0, cA1);
        SMH(1, cB0, cB1);
        PVH(cur, 0, cA0, cA1);
        PVH(cur, 1, cB0, cB1);
        // head pair {2,3}
        QKH(cur, 2, cA0, cA1);
        QKH(cur, 3, cB0, cB1);
        if (t + 1 < NTS_) MLOADX(kk + KV_);   // mr dead after QKH(3) C-init
        SMH(2, cA0, cA1);
        SMH(3, cB0, cB1);
        PVH(cur, 2, cA0, cA1);
        PVH(cur, 3, cB0, cB1);
        __syncthreads();                      // drain: next tile staged
    }

    // ---- partial epilogue per head: normalized O (f16) + lse (f32, log2) ----
#pragma unroll
    for (int H = 0; H < HG_; ++H) {
        const float inv = 1.f / srun[H];
        const float lse = mrun[H] + lg2(srun[H]);
        unsigned short* pob = po + ((size_t)((sp * B_ + b) * NH_ + hbase + H) * HD_) * L_ + qrow;
#pragma unroll
        for (int i = 0; i < 16; ++i) {
            const int d = (i & 3) + 8 * (i >> 2) + 4 * hi;
            if (d < HD_) {
                union { __fp16 hf; unsigned short us; } cv;
                cv.hf = (__fp16)(o[H][i] * inv);
                pob[(size_t)d * L_] = cv.us;
            }
        }
        if (hi == 0)
            pms[((size_t)(sp * B_ + b) * NH_ + hbase + H) * L_ + qrow] = lse;
    }
#undef STAGE
#undef MLOADX
#undef MSCALE
#undef QKH
#undef SMH
#undef PVH
}

// ---------------------------------------------------------------------------
// Combine the 4 KV-split partials.
// ---------------------------------------------------------------------------
__global__ __launch_bounds__(256) void combine_kernel(const unsigned short* __restrict__ po,
                                                      const float* __restrict__ pms,
                                                      float* __restrict__ att) {
    const int qrow = blockIdx.x * 256 + threadIdx.x;
    const int h    = blockIdx.y;
    const int b    = blockIdx.z;

    float l[NSPL_];
#pragma unroll
    for (int s = 0; s < NSPL_; ++s)
        l[s] = pms[((size_t)(s * B_ + b) * NH_ + h) * L_ + qrow];
    float lm = l[0];
#pragma unroll
    for (int s = 1; s < NSPL_; ++s) lm = fmaxf(lm, l[s]);
    float wv[NSPL_], wsum = 0.f;
#pragma unroll
    for (int s = 0; s < NSPL_; ++s) { wv[s] = ex2(l[s] - lm); wsum += wv[s]; }
    const float inv = 1.f / wsum;

    float* op = att + ((size_t)b * C_ + h * HD_) * L_ + qrow;
#pragma unroll
    for (int d = 0; d < HD_; ++d) {
        float acc = 0.f;
#pragma unroll
        for (int s = 0; s < NSPL_; ++s) {
            union { unsigned short us; __fp16 hf; } cv;
            cv.us = po[(((size_t)(s * B_ + b) * NH_ + h) * HD_ + d) * L_ + qrow];
            acc += (float)cv.hf * wv[s];
        }
        op[(size_t)d * L_] = acc * inv;
    }
}

// ---------------------------------------------------------------------------
extern "C" void kernel_launch(void* const* d_in, const int* in_sizes, int n_in,
                              void* d_out, int out_size, void* d_ws, size_t ws_size,
                              hipStream_t stream) {
    const float* x      = (const float*)d_in[0];
    const float* mask   = (const float*)d_in[1];
    const float* w_qkv  = (const float*)d_in[2];
    const float* b_qkv  = (const float*)d_in[3];
    const float* w_proj = (const float*)d_in[4];
    const float* b_proj = (const float*)d_in[5];
    float* out = (float*)d_out;

    unsigned int*   q2  = (unsigned int*)d_ws;                                // B*8*12*L u32
    unsigned int*   k2t = q2 + (size_t)B_ * NH_ * 12 * L_;                    // B*8*L*20 u32
    unsigned short* v16 = (unsigned short*)(k2t + (size_t)B_ * NH_ * L_ * KSTR_); // B*8*24*L u16
    unsigned short* po  = v16 + (size_t)B_ * NH_ * HD_ * L_;                  // 4*B*8*24*L u16
    float* pms    = (float*)(po + (size_t)NSPL_ * B_ * NH_ * HD_ * L_);       // 4*B*8*L f32
    float* ws_att = pms + (size_t)NSPL_ * B_ * NH_ * L_;                      // B*192*L f32

    lin_qkv<<<dim3(72, 32), 256, 0, stream>>>(x, w_qkv, b_qkv, q2, k2t, v16);
    attn_mfma<<<dim3(512), 256, 0, stream>>>(q2, k2t, v16, mask, po, pms);
    combine_kernel<<<dim3(16, NH_, B_), 256, 0, stream>>>(po, pms, ws_att);
    lin_kernel<<<dim3(24, 32), 256, 0, stream>>>(ws_att, w_proj, b_proj, out, C_);
}